// Round 1
// baseline (130.798 us; speedup 1.0000x reference)
//
#include <hip/hip_runtime.h>

#define IMG_H 256
#define IMG_W 256
#define TILE 32
#define HALO 38   // TILE + 6
#define LDS_STRIDE 40

// Kernel 1: fused depthwise 7x7 gaussian conv (5 fields) + SSIM map + block reduction.
// One block per 32x32 output tile of one plane. Block = 32x8 threads, 4 rows/thread.
__global__ __launch_bounds__(256) void ssim_tile_kernel(
    const float* __restrict__ x, const float* __restrict__ y,
    float* __restrict__ partial) {
    __shared__ float sxs[HALO][LDS_STRIDE];
    __shared__ float sys[HALO][LDS_STRIDE];

    const int tx = threadIdx.x;          // 0..31
    const int ty = threadIdx.y;          // 0..7
    const int tid = ty * 32 + tx;        // 0..255
    const int plane = blockIdx.z;        // 0..191
    const int r0 = (int)blockIdx.y * TILE - 3;
    const int c0 = (int)blockIdx.x * TILE - 3;
    const size_t base = (size_t)plane * (IMG_H * IMG_W);

    // Stage halo tiles (zero padding out of bounds)
    for (int i = tid; i < HALO * HALO; i += 256) {
        int r = i / HALO;
        int c = i - r * HALO;
        int gr = r0 + r;
        int gc = c0 + c;
        float xv = 0.f, yv = 0.f;
        if ((unsigned)gr < IMG_H && (unsigned)gc < IMG_W) {
            size_t idx = base + (size_t)gr * IMG_W + gc;
            xv = x[idx];
            yv = y[idx];
        }
        sxs[r][c] = xv;
        sys[r][c] = yv;
    }

    // Gaussian coefficients (uniform across threads, matches numpy f32 recipe)
    float g[7];
    {
        float s = 0.f;
        #pragma unroll
        for (int i = 0; i < 7; i++) {
            float d = (float)(i - 3);
            g[i] = expf(-(d * d) / 4.5f);
            s += g[i];
        }
        float inv = 1.f / s;
        #pragma unroll
        for (int i = 0; i < 7; i++) g[i] *= inv;
    }

    __syncthreads();

    const float c1 = 0.01f * 0.01f;
    const float c2 = 0.03f * 0.03f;

    float acc = 0.f;
    #pragma unroll
    for (int k = 0; k < 4; k++) {
        const int row = ty + k * 8;   // 0..31 output row in tile
        const int col = tx;           // 0..31 output col in tile
        float sx = 0.f, sy = 0.f, sxx = 0.f, syy = 0.f, sxy = 0.f;
        #pragma unroll
        for (int dy = 0; dy < 7; dy++) {
            float rsx = 0.f, rsy = 0.f, rsxx = 0.f, rsyy = 0.f, rsxy = 0.f;
            #pragma unroll
            for (int dx = 0; dx < 7; dx++) {
                float xv = sxs[row + dy][col + dx];
                float yv = sys[row + dy][col + dx];
                float gw = g[dx];
                float t1 = gw * xv;
                float t2 = gw * yv;
                rsx += t1;
                rsy += t2;
                rsxx = fmaf(t1, xv, rsxx);
                rsyy = fmaf(t2, yv, rsyy);
                rsxy = fmaf(t1, yv, rsxy);
            }
            float gy = g[dy];
            sx  = fmaf(gy, rsx,  sx);
            sy  = fmaf(gy, rsy,  sy);
            sxx = fmaf(gy, rsxx, sxx);
            syy = fmaf(gy, rsyy, syy);
            sxy = fmaf(gy, rsxy, sxy);
        }
        float mu1s = sx * sx;
        float mu2s = sy * sy;
        float mu12 = sx * sy;
        float s1  = sxx - mu1s;
        float s2  = syy - mu2s;
        float s12 = sxy - mu12;
        float num = (2.f * mu12 + c1) * (2.f * s12 + c2);
        float den = (mu1s + mu2s + c1) * (s1 + s2 + c2);
        acc += num / den;
    }

    // Wave (64-lane) shuffle reduction, then cross-wave via LDS
    #pragma unroll
    for (int off = 32; off > 0; off >>= 1)
        acc += __shfl_down(acc, off, 64);

    __shared__ float wsum[4];
    const int wave = tid >> 6;
    const int lane = tid & 63;
    if (lane == 0) wsum[wave] = acc;
    __syncthreads();
    if (tid == 0) {
        float t = wsum[0] + wsum[1] + wsum[2] + wsum[3];
        partial[((size_t)blockIdx.z * 64) + blockIdx.y * 8 + blockIdx.x] = t;
    }
}

// Kernel 2: deterministic final reduction (single block, double accumulation)
__global__ __launch_bounds__(256) void ssim_reduce_kernel(
    const float* __restrict__ partial, float* __restrict__ out,
    int n, double inv_count) {
    __shared__ double sd[256];
    double a = 0.0;
    for (int i = threadIdx.x; i < n; i += 256) a += (double)partial[i];
    sd[threadIdx.x] = a;
    __syncthreads();
    for (int s = 128; s > 0; s >>= 1) {
        if ((int)threadIdx.x < s) sd[threadIdx.x] += sd[threadIdx.x + s];
        __syncthreads();
    }
    if (threadIdx.x == 0) out[0] = (float)(sd[0] * inv_count);
}

extern "C" void kernel_launch(void* const* d_in, const int* in_sizes, int n_in,
                              void* d_out, int out_size, void* d_ws, size_t ws_size,
                              hipStream_t stream) {
    const float* x = (const float*)d_in[0];
    const float* y = (const float*)d_in[1];
    float* out = (float*)d_out;
    float* partial = (float*)d_ws;

    const int total = in_sizes[0];                 // 12,582,912
    const int planes = total / (IMG_H * IMG_W);    // 192
    const int tiles_r = IMG_H / TILE;              // 8
    const int tiles_c = IMG_W / TILE;              // 8
    const int n_partial = planes * tiles_r * tiles_c;  // 12288

    dim3 grid(tiles_c, tiles_r, planes);
    dim3 block(32, 8);
    ssim_tile_kernel<<<grid, block, 0, stream>>>(x, y, partial);

    ssim_reduce_kernel<<<1, 256, 0, stream>>>(partial, out, n_partial,
                                              1.0 / (double)total);
}

// Round 2
// 75.408 us; speedup vs baseline: 1.7345x; 1.7345x over previous
//
#include <hip/hip_runtime.h>

#define IMG_H 256
#define IMG_W 256
#define TW 64
#define TH 16
#define HW 70   // TW + 6
#define HH 22   // TH + 6
#define VSTRIDE 73  // padded plane stride: 73%32=9 -> strided reads are 2-way (free)

// Fused SSIM: stage x,y -> vertical gaussian (5 fields) -> horizontal gaussian
// -> SSIM map -> block reduction. One block per 64x16 tile. 256 threads.
__global__ __launch_bounds__(256) void ssim_tile_kernel(
    const float* __restrict__ x, const float* __restrict__ y,
    float* __restrict__ partial) {
    __shared__ float sxy[HH][HW][2];        // 12320 B
    __shared__ float vs[5][TH][VSTRIDE];    // 23360 B

    const int tid = threadIdx.x;
    const int plane = blockIdx.z;
    const int r0 = (int)blockIdx.y * TH - 3;
    const int c0 = (int)blockIdx.x * TW - 3;
    const size_t base = (size_t)plane * (IMG_H * IMG_W);

    // Gaussian weights (uniform across threads; matches numpy f32 recipe)
    float g[7];
    {
        float s = 0.f;
        #pragma unroll
        for (int i = 0; i < 7; i++) {
            float d = (float)(i - 3);
            g[i] = expf(-(d * d) / 4.5f);
            s += g[i];
        }
        float inv = 1.f / s;
        #pragma unroll
        for (int i = 0; i < 7; i++) g[i] *= inv;
    }

    // ---- Stage x,y halo (zero-pad OOB), interleaved pairs ----
    for (int i = tid; i < HH * HW; i += 256) {
        int rr = i / HW;
        int cc = i - rr * HW;
        int gr = r0 + rr;
        int gc = c0 + cc;
        float xv = 0.f, yv = 0.f;
        if ((unsigned)gr < IMG_H && (unsigned)gc < IMG_W) {
            size_t idx = base + (size_t)gr * IMG_W + gc;
            xv = x[idx];
            yv = y[idx];
        }
        sxy[rr][cc][0] = xv;
        sxy[rr][cc][1] = yv;
    }
    __syncthreads();

    // ---- Vertical pass: each task computes 4 consecutive output rows at one col ----
    // 280 tasks = 4 row-groups x 70 cols. 10 taps shared across the 4 outputs.
    for (int i = tid; i < 4 * HW; i += 256) {
        int a = i / HW;           // row group 0..3
        int c = i - a * HW;       // 0..69
        int rb = a * 4;           // output rows rb..rb+3
        float acc[4][5];
        #pragma unroll
        for (int o = 0; o < 4; o++)
            #pragma unroll
            for (int f = 0; f < 5; f++) acc[o][f] = 0.f;

        #pragma unroll
        for (int t = 0; t < 10; t++) {
            float xv = sxy[rb + t][c][0];
            float yv = sxy[rb + t][c][1];
            float xx = xv * xv;
            float yy = yv * yv;
            float xy = xv * yv;
            #pragma unroll
            for (int o = 0; o < 4; o++) {
                const int dy = t - o;
                if (dy >= 0 && dy < 7) {
                    float gw = g[dy];
                    acc[o][0] = fmaf(gw, xv, acc[o][0]);
                    acc[o][1] = fmaf(gw, yv, acc[o][1]);
                    acc[o][2] = fmaf(gw, xx, acc[o][2]);
                    acc[o][3] = fmaf(gw, yy, acc[o][3]);
                    acc[o][4] = fmaf(gw, xy, acc[o][4]);
                }
            }
        }
        #pragma unroll
        for (int o = 0; o < 4; o++) {
            vs[0][rb + o][c] = acc[o][0];
            vs[1][rb + o][c] = acc[o][1];
            vs[2][rb + o][c] = acc[o][2];
            vs[3][rb + o][c] = acc[o][3];
            vs[4][rb + o][c] = acc[o][4];
        }
    }
    __syncthreads();

    // ---- Horizontal pass: each thread does 4 consecutive pixels in one row ----
    const int m = tid & 15;       // col group -> cols 4m..4m+3
    const int r = tid >> 4;       // row 0..15
    const int cb = m * 4;

    float sacc[4][5];
    #pragma unroll
    for (int f = 0; f < 5; f++) {
        float w[10];
        #pragma unroll
        for (int j = 0; j < 10; j++) w[j] = vs[f][r][cb + j];
        #pragma unroll
        for (int q = 0; q < 4; q++) {
            float s = 0.f;
            #pragma unroll
            for (int dx = 0; dx < 7; dx++) s = fmaf(g[dx], w[q + dx], s);
            sacc[q][f] = s;
        }
    }

    const float c1 = 0.01f * 0.01f;
    const float c2 = 0.03f * 0.03f;
    float acc = 0.f;
    #pragma unroll
    for (int q = 0; q < 4; q++) {
        float sx  = sacc[q][0];
        float sy  = sacc[q][1];
        float sxx = sacc[q][2];
        float syy = sacc[q][3];
        float sxy2 = sacc[q][4];
        float mu1s = sx * sx;
        float mu2s = sy * sy;
        float mu12 = sx * sy;
        float s1  = sxx - mu1s;
        float s2  = syy - mu2s;
        float s12 = sxy2 - mu12;
        float num = fmaf(2.f, mu12, c1) * fmaf(2.f, s12, c2);
        float den = (mu1s + mu2s + c1) * (s1 + s2 + c2);
        float rcp = __builtin_amdgcn_rcpf(den);
        rcp = rcp * (2.f - den * rcp);   // 1 Newton step
        acc = fmaf(num, rcp, acc);
    }

    // ---- Block reduction ----
    #pragma unroll
    for (int off = 32; off > 0; off >>= 1)
        acc += __shfl_down(acc, off, 64);

    __shared__ float wsum[4];
    const int wave = tid >> 6;
    const int lane = tid & 63;
    if (lane == 0) wsum[wave] = acc;
    __syncthreads();
    if (tid == 0) {
        float t = wsum[0] + wsum[1] + wsum[2] + wsum[3];
        partial[((size_t)blockIdx.z * 64) + blockIdx.y * 4 + blockIdx.x] = t;
    }
}

// Deterministic final reduction: single block, 1024 threads, double accumulation.
__global__ __launch_bounds__(1024) void ssim_reduce_kernel(
    const float4* __restrict__ p, float* __restrict__ out,
    int n4, double inv_count) {
    double a = 0.0;
    for (int i = threadIdx.x; i < n4; i += 1024) {
        float4 v = p[i];
        a += (double)v.x + (double)v.y + (double)v.z + (double)v.w;
    }
    #pragma unroll
    for (int off = 32; off > 0; off >>= 1)
        a += __shfl_down(a, off, 64);
    __shared__ double sd[16];
    const int wave = threadIdx.x >> 6;
    const int lane = threadIdx.x & 63;
    if (lane == 0) sd[wave] = a;
    __syncthreads();
    if (threadIdx.x == 0) {
        double t = 0.0;
        #pragma unroll
        for (int w = 0; w < 16; w++) t += sd[w];
        out[0] = (float)(t * inv_count);
    }
}

extern "C" void kernel_launch(void* const* d_in, const int* in_sizes, int n_in,
                              void* d_out, int out_size, void* d_ws, size_t ws_size,
                              hipStream_t stream) {
    const float* x = (const float*)d_in[0];
    const float* y = (const float*)d_in[1];
    float* out = (float*)d_out;
    float* partial = (float*)d_ws;

    const int total = in_sizes[0];                 // 12,582,912
    const int planes = total / (IMG_H * IMG_W);    // 192
    const int tiles_r = IMG_H / TH;                // 16
    const int tiles_c = IMG_W / TW;                // 4
    const int n_partial = planes * tiles_r * tiles_c;  // 12288

    dim3 grid(tiles_c, tiles_r, planes);
    dim3 block(256);
    ssim_tile_kernel<<<grid, block, 0, stream>>>(x, y, partial);

    ssim_reduce_kernel<<<1, 1024, 0, stream>>>((const float4*)partial, out,
                                               n_partial / 4, 1.0 / (double)total);
}